// Round 5
// baseline (314.009 us; speedup 1.0000x reference)
//
#include <hip/hip_runtime.h>

typedef unsigned short u16;
typedef __attribute__((ext_vector_type(8))) short bf16x8;
typedef __attribute__((ext_vector_type(4))) float f32x4;

#define MFMA16(a,b,c) __builtin_amdgcn_mfma_f32_16x16x32_bf16((a),(b),(c),0,0,0)

__device__ __forceinline__ float b2f(u16 u){
  unsigned v = ((unsigned)u) << 16; float f;
  __builtin_memcpy(&f, &v, 4); return f;
}
__device__ __forceinline__ u16 f2b(float f){
  unsigned v; __builtin_memcpy(&v, &f, 4);
  v += 0x7FFFu + ((v >> 16) & 1u);
  return (u16)(v >> 16);
}
__device__ __forceinline__ float scrub(float v, float lim){
  return fminf(fmaxf(v, -lim), lim);   // NaN-filtering clamp
}
__device__ __forceinline__ void gload16(const void* g, void* l){
  __builtin_amdgcn_global_load_lds(
      (const __attribute__((address_space(1))) unsigned int*)g,
      (__attribute__((address_space(3))) unsigned int*)l, 16, 0, 0);
}

// ---- convert+transpose tile helper: dst[c][r] = bf16(src[r][c]) ----
__device__ __forceinline__ void cvtT_tile(float (*tile)[33],
    u16* __restrict__ dst, const float* __restrict__ src,
    int rows, int cols, int bx, int by, int tid){
  int n0 = bx * 32, r0 = by * 32;
  int tx = tid & 31, ty = tid >> 5;
#pragma unroll
  for (int i = 0; i < 4; i++)
    tile[ty + i * 8][tx] = src[(size_t)(r0 + ty + i * 8) * cols + n0 + tx];
  __syncthreads();
#pragma unroll
  for (int i = 0; i < 4; i++)
    dst[(size_t)(n0 + ty + i * 8) * rows + r0 + tx] = f2b(tile[tx][ty + i * 8]);
}

// ---- prep1: x -> bf16 (5760 blocks) + WqT (11520 blocks) ----
__global__ __launch_bounds__(256) void k_prep1(
    u16* __restrict__ xb, const float* __restrict__ x,
    u16* __restrict__ wqT, const float* __restrict__ Wq){
  __shared__ float tile[32][33];
  int b = blockIdx.x, tid = threadIdx.x;
  if (b < 5760){
    int i = b * 256 + tid;
    float4 v = ((const float4*)x)[i];
    u16 o[4] = { f2b(v.x), f2b(v.y), f2b(v.z), f2b(v.w) };
    *(uint2*)&xb[(size_t)i * 4] = *(const uint2*)o;
    return;
  }
  b -= 5760;
  cvtT_tile(tile, wqT, Wq, 2880, 4096, b % 128, b / 128, tid);
}

// ---- prep2: WkT + WvT (1440 each) + bkv pack (4 blocks) ----
__global__ __launch_bounds__(256) void k_prep2(
    u16* __restrict__ wkvT, const float* __restrict__ Wk,
    const float* __restrict__ Wv, float* __restrict__ bkv,
    const float* __restrict__ bk, const float* __restrict__ bv){
  __shared__ float tile[32][33];
  int b = blockIdx.x, tid = threadIdx.x;
  if (b < 1440){ cvtT_tile(tile, wkvT, Wk, 2880, 512, b % 16, b / 16, tid); return; }
  b -= 1440;
  if (b < 1440){ cvtT_tile(tile, wkvT + (size_t)512 * 2880, Wv, 2880, 512, b % 16, b / 16, tid); return; }
  b -= 1440;
  int n = b * 256 + tid;
  if (n < 1024) bkv[n] = (n < 512) ? bk[n] : bv[n - 512];
}

// ---- prep3: WoT (11520 blocks) ----
__global__ __launch_bounds__(256) void k_prep3(
    u16* __restrict__ woT, const float* __restrict__ Wo){
  __shared__ float tile[32][33];
  int b = blockIdx.x, tid = threadIdx.x;
  cvtT_tile(tile, woT, Wo, 4096, 2880, b % 90, b / 90, tid);
}

// -------- GEMM: C[M][ldc] <- A[M][K](bf16) * BT[N][K]^T(bf16) + bias(f32) --------
// 64x64 tile, BK=32, 4 waves (2x2), acc[2][2]. Max-TLP variant: 8 blocks/CU.
template<int F32OUT>
__global__ __launch_bounds__(256) void k_gemm64(
    const u16* __restrict__ A, const u16* __restrict__ BT,
    const float* __restrict__ bias, void* __restrict__ C,
    int M, int N, int K, int ldc){
  __shared__ u16 As[64 * 32];
  __shared__ u16 Bs[64 * 32];
  int mt_count = M >> 6;
  int bid = blockIdx.x;
  int mt = bid % mt_count, nt = bid / mt_count;
  int m0 = mt << 6, n0 = nt << 6;
  int tid = threadIdx.x;
  int w = tid >> 6, l = tid & 63;
  int wm = w >> 1, wn = w & 1;
  int lr = l & 15, lh = l >> 4;
  int srow = tid >> 2, skc = (tid & 3) << 3;   // staging: row 0..63, k-chunk

  f32x4 acc[2][2];
#pragma unroll
  for (int m = 0; m < 2; m++)
#pragma unroll
    for (int n = 0; n < 2; n++){ acc[m][n][0]=0.f; acc[m][n][1]=0.f; acc[m][n][2]=0.f; acc[m][n][3]=0.f; }

  const u16* arow = &A[(size_t)(m0 + srow) * K + skc];
  const u16* brow = &BT[(size_t)(n0 + srow) * K + skc];

  for (int kt = 0; kt < K; kt += 32){
    gload16(arow + kt, &As[tid * 8]);
    gload16(brow + kt, &Bs[tid * 8]);
    __syncthreads();

    bf16x8 af[2], bfr[2];
#pragma unroll
    for (int m = 0; m < 2; m++)
      af[m] = *(const bf16x8*)&As[(wm * 32 + m * 16 + lr) * 32 + (lh << 3)];
#pragma unroll
    for (int n = 0; n < 2; n++)
      bfr[n] = *(const bf16x8*)&Bs[(wn * 32 + n * 16 + lr) * 32 + (lh << 3)];
#pragma unroll
    for (int m = 0; m < 2; m++)
#pragma unroll
      for (int n = 0; n < 2; n++)
        acc[m][n] = MFMA16(af[m], bfr[n], acc[m][n]);
    __syncthreads();
  }

#pragma unroll
  for (int m = 0; m < 2; m++){
    int row = m0 + wm * 32 + m * 16 + (lh << 2);
#pragma unroll
    for (int n = 0; n < 2; n++){
      int col = n0 + wn * 32 + n * 16 + lr;
      float bs = bias[col];
#pragma unroll
      for (int r = 0; r < 4; r++){
        float v = scrub(acc[m][n][r] + bs, 1e9f);
        size_t off = (size_t)(row + r) * ldc + col;
        if (F32OUT) ((float*)C)[off] = v;
        else        ((u16*)C)[off]   = f2b(v);
      }
    }
  }
}

// ---------------- RoPE in-place on qkv[2048][5120] (bf16) ----------------
__global__ __launch_bounds__(256) void k_rope(u16* __restrict__ qkv,
                                              const int* __restrict__ pos){
  int idx = blockIdx.x * 256 + threadIdx.x;
  const int TOTAL = 2048 * 2304;
  if (idx >= TOTAL) return;
  int r = idx / 2304, u = idx - r * 2304;
  int i, col;
  if (u < 2048){ i = u & 31; col = (u >> 5) * 64 + (i << 1); }
  else { int u2 = u - 2048; i = u2 & 31; col = 4096 + (u2 >> 5) * 64 + (i << 1); }
  float p = (float)pos[r];
  float inv = powf(150000.0f, -((float)(2 * i)) / 64.0f);
  float f = (p / 32.0f) * inv;
  float s, c;
  __sincosf(f, &s, &c);
  size_t base = (size_t)r * 5120 + col;
  float x1 = b2f(qkv[base]), x2 = b2f(qkv[base + 1]);
  qkv[base]     = f2b(x1 * c - x2 * s);
  qkv[base + 1] = f2b(x1 * s + x2 * c);
}

// ---------------- attention ----------------
__global__ __launch_bounds__(256) void k_attn(
    const u16* __restrict__ qkv, const float* __restrict__ sink,
    u16* __restrict__ y, const int* __restrict__ slide_p,
    const int* __restrict__ win_p){
  __shared__ u16 Ks[64][72];
  __shared__ u16 VTs[64][72];
  __shared__ u16 Plds[4][32][72];

  int bid = blockIdx.x;
  int qt = bid & 7, h = (bid >> 3) & 63, b = bid >> 9;
  int t0 = qt << 7;
  int g = h >> 3;
  int kcol = 4096 + g * 64, vcol = 4608 + g * 64;
  int tid = threadIdx.x, w = tid >> 6, l = tid & 63;
  int lr = l & 15, lh = l >> 4;
  int win = (*slide_p) ? (*win_p) : (1 << 30);
  int tq0 = t0 + w * 32;

  bf16x8 qf[2][2];
#pragma unroll
  for (int m = 0; m < 2; m++)
#pragma unroll
    for (int kk = 0; kk < 2; kk++){
      int q = tq0 + m * 16 + lr;
      qf[m][kk] = *(const bf16x8*)&qkv[(size_t)(b * 1024 + q) * 5120 + h * 64 + kk * 32 + lh * 8];
    }

  float run_max[2] = {-1e30f, -1e30f};
  float run_sum[2] = {0.f, 0.f};
  f32x4 acc_o[4][2];
#pragma unroll
  for (int dt = 0; dt < 4; dt++)
#pragma unroll
    for (int m = 0; m < 2; m++){ acc_o[dt][m][0]=0.f; acc_o[dt][m][1]=0.f; acc_o[dt][m][2]=0.f; acc_o[dt][m][3]=0.f; }

  for (int c = 0; c < 4; c++){
    int key0 = t0 - 128 + c * 64;
#pragma unroll
    for (int it = 0; it < 2; ++it){
      int idx = it * 256 + tid;
      int key = idx >> 3, dd = (idx & 7) << 3;
      int gk = key0 + key;
      uint4 kq = make_uint4(0, 0, 0, 0);
      uint4 vq = make_uint4(0, 0, 0, 0);
      if (gk >= 0){
        size_t rb = (size_t)(b * 1024 + gk) * 5120;
        kq = *(const uint4*)&qkv[rb + kcol + dd];
        vq = *(const uint4*)&qkv[rb + vcol + dd];
      }
      *(uint4*)&Ks[key][dd] = kq;
      const u16* tv = (const u16*)&vq;
#pragma unroll
      for (int j = 0; j < 8; j++) VTs[dd + j][key] = tv[j];
    }
    __syncthreads();

    bool rel = (key0 + 63 >= tq0 - (win - 1)) && (key0 <= tq0 + 31);
    if (rel){
      f32x4 sacc[2][4];
#pragma unroll
      for (int m = 0; m < 2; m++)
#pragma unroll
        for (int n = 0; n < 4; n++){ sacc[m][n][0]=0.f; sacc[m][n][1]=0.f; sacc[m][n][2]=0.f; sacc[m][n][3]=0.f; }
#pragma unroll
      for (int kk = 0; kk < 2; kk++){
#pragma unroll
        for (int n = 0; n < 4; n++){
          bf16x8 kf = *(const bf16x8*)&Ks[n * 16 + lr][kk * 32 + lh * 8];
          sacc[0][n] = MFMA16(kf, qf[0][kk], sacc[0][n]);
          sacc[1][n] = MFMA16(kf, qf[1][kk], sacc[1][n]);
        }
      }
#pragma unroll
      for (int m = 0; m < 2; m++){
        int qrow = tq0 + m * 16 + lr;
        float cmax = -INFINITY;
#pragma unroll
        for (int n = 0; n < 4; n++)
#pragma unroll
          for (int r = 0; r < 4; r++){
            int key = key0 + n * 16 + lh * 4 + r;
            float s = scrub(sacc[m][n][r] * 0.125f, 1e30f);
            bool valid = (key >= 0) && (key <= qrow) && (qrow - key < win);
            s = valid ? s : -INFINITY;
            sacc[m][n][r] = s;
            cmax = fmaxf(cmax, s);
          }
        cmax = fmaxf(cmax, __shfl_xor(cmax, 16));
        cmax = fmaxf(cmax, __shfl_xor(cmax, 32));
        float mnew = fmaxf(run_max[m], cmax);
        float corr = __expf(run_max[m] - mnew);
        run_max[m] = mnew;
        float rsum = 0.f;
#pragma unroll
        for (int n = 0; n < 4; n++)
#pragma unroll
          for (int r = 0; r < 4; r++){
            float p = __expf(sacc[m][n][r] - mnew);
            sacc[m][n][r] = p;
            rsum += p;
          }
        rsum += __shfl_xor(rsum, 16);
        rsum += __shfl_xor(rsum, 32);
        run_sum[m] = run_sum[m] * corr + rsum;
#pragma unroll
        for (int dt = 0; dt < 4; dt++) acc_o[dt][m] *= corr;
#pragma unroll
        for (int n = 0; n < 4; n++)
#pragma unroll
          for (int r = 0; r < 4; r++)
            Plds[w][m * 16 + lr][n * 16 + lh * 4 + r] = f2b(sacc[m][n][r]);
      }
#pragma unroll
      for (int ks = 0; ks < 2; ks++){
        bf16x8 pb[2];
#pragma unroll
        for (int m = 0; m < 2; m++)
          pb[m] = *(const bf16x8*)&Plds[w][m * 16 + lr][ks * 32 + lh * 8];
#pragma unroll
        for (int dt = 0; dt < 4; dt++){
          bf16x8 vf = *(const bf16x8*)&VTs[dt * 16 + lr][ks * 32 + lh * 8];
          acc_o[dt][0] = MFMA16(vf, pb[0], acc_o[dt][0]);
          acc_o[dt][1] = MFMA16(vf, pb[1], acc_o[dt][1]);
        }
      }
    }
    __syncthreads();
  }

  float sk = sink[h];
  float osc[2];
#pragma unroll
  for (int m = 0; m < 2; m++){
    float Mf = fmaxf(run_max[m], sk);
    float t = __expf(run_max[m] - Mf);
    float denom = run_sum[m] * t + __expf(sk - Mf);
    osc[m] = t / denom;
  }
#pragma unroll
  for (int dt = 0; dt < 4; dt++)
#pragma unroll
    for (int m = 0; m < 2; m++)
#pragma unroll
      for (int r = 0; r < 4; r++){
        int d = dt * 16 + lh * 4 + r;
        int q = tq0 + m * 16 + lr;
        y[(size_t)(b * 1024 + q) * 4096 + h * 64 + d] = f2b(scrub(acc_o[dt][m][r] * osc[m], 1e9f));
      }
}

// ---------------- host ----------------
extern "C" void kernel_launch(void* const* d_in, const int* in_sizes, int n_in,
                              void* d_out, int out_size, void* d_ws, size_t ws_size,
                              hipStream_t stream){
  const float* x    = (const float*)d_in[0];
  const int*   pos  = (const int*)d_in[1];
  const float* Wq   = (const float*)d_in[3];
  const float* bq   = (const float*)d_in[4];
  const float* Wk   = (const float*)d_in[5];
  const float* bk   = (const float*)d_in[6];
  const float* Wv   = (const float*)d_in[7];
  const float* bv   = (const float*)d_in[8];
  const float* Wo   = (const float*)d_in[9];
  const float* bo   = (const float*)d_in[10];
  const float* sink = (const float*)d_in[11];
  const int* slide  = (const int*)d_in[12];
  const int* winp   = (const int*)d_in[13];
  float* out = (float*)d_out;

  // Workspace (61.35 MB peak, proven):
  //   [0, 16.78M)        xb [2048][2880] bf16 -> ybuf [2048][4096] bf16 (xb dead at attn)
  //   [16.78M, 37.75M)   qkv [2048][5120] bf16
  //   [37.75M, 61.34M)   W region: wqT -> wkvT -> woT (sequential reuse)
  //   [61.34M, +4K)      bkv fp32[1024]
  char* ws = (char*)d_ws;
  u16*   xb   = (u16*)(ws + 0);
  u16*   ybuf = (u16*)(ws + 0);
  u16*   qkv  = (u16*)(ws + 16777216);
  u16*   wqT  = (u16*)(ws + 37748736);
  u16*   wkvT = (u16*)(ws + 37748736);
  u16*   woT  = (u16*)(ws + 37748736);
  float* bkv  = (float*)(ws + 61341696);

  // prep1: x->bf16 + WqT
  k_prep1<<<5760 + 11520, 256, 0, stream>>>(xb, x, wqT, Wq);
  // Q projection: M=2048,N=4096,K=2880 -> 32x64 = 2048 WGs (8 blocks/CU)
  k_gemm64<0><<<32 * 64, 256, 0, stream>>>(xb, wqT, bq, qkv, 2048, 4096, 2880, 5120);
  // prep2: WkT+WvT+bkv (W region reuse after gemm1-Q)
  k_prep2<<<1440 + 1440 + 4, 256, 0, stream>>>(wkvT, Wk, Wv, bkv, bk, bv);
  // KV projection: N=1024 -> 32x16 = 512 WGs
  k_gemm64<0><<<32 * 16, 256, 0, stream>>>(xb, wkvT, bkv, qkv + 4096, 2048, 1024, 2880, 5120);
  // RoPE
  k_rope<<<(2048 * 2304 + 255) / 256, 256, 0, stream>>>(qkv, pos);
  // prep3: WoT (W region dead again)
  k_prep3<<<11520, 256, 0, stream>>>(woT, Wo);
  // attention
  k_attn<<<1024, 256, 0, stream>>>(qkv, sink, ybuf, slide, winp);
  // output projection: M=2048,N=2880,K=4096 -> 32x45 = 1440 WGs (fp32 out)
  k_gemm64<1><<<32 * 45, 256, 0, stream>>>(ybuf, woT, bo, out, 2048, 2880, 4096, 2880);
}

// Round 6
// 250.212 us; speedup vs baseline: 1.2550x; 1.2550x over previous
//
#include <hip/hip_runtime.h>

typedef unsigned short u16;
typedef __attribute__((ext_vector_type(8))) short bf16x8;
typedef __attribute__((ext_vector_type(4))) float f32x4;

#define MFMA16(a,b,c) __builtin_amdgcn_mfma_f32_16x16x32_bf16((a),(b),(c),0,0,0)

__device__ __forceinline__ float b2f(u16 u){
  unsigned v = ((unsigned)u) << 16; float f;
  __builtin_memcpy(&f, &v, 4); return f;
}
__device__ __forceinline__ u16 f2b(float f){
  unsigned v; __builtin_memcpy(&v, &f, 4);
  v += 0x7FFFu + ((v >> 16) & 1u);
  return (u16)(v >> 16);
}
__device__ __forceinline__ float scrub(float v, float lim){
  return fminf(fmaxf(v, -lim), lim);   // NaN-filtering clamp
}
__device__ __forceinline__ void gload16(const void* g, void* l){
  __builtin_amdgcn_global_load_lds(
      (const __attribute__((address_space(1))) unsigned int*)g,
      (__attribute__((address_space(3))) unsigned int*)l, 16, 0, 0);
}

// ---- convert+transpose tile helper: dst[c][r] = bf16(src[r][c]) ----
__device__ __forceinline__ void cvtT_tile(float (*tile)[33],
    u16* __restrict__ dst, const float* __restrict__ src,
    int rows, int cols, int bx, int by, int tid){
  int n0 = bx * 32, r0 = by * 32;
  int tx = tid & 31, ty = tid >> 5;
#pragma unroll
  for (int i = 0; i < 4; i++)
    tile[ty + i * 8][tx] = src[(size_t)(r0 + ty + i * 8) * cols + n0 + tx];
  __syncthreads();
#pragma unroll
  for (int i = 0; i < 4; i++)
    dst[(size_t)(n0 + ty + i * 8) * rows + r0 + tx] = f2b(tile[tx][ty + i * 8]);
}

// ---- prep1: x -> bf16 (5760 blocks) + WqT (11520 blocks) ----
__global__ __launch_bounds__(256) void k_prep1(
    u16* __restrict__ xb, const float* __restrict__ x,
    u16* __restrict__ wqT, const float* __restrict__ Wq){
  __shared__ float tile[32][33];
  int b = blockIdx.x, tid = threadIdx.x;
  if (b < 5760){
    int i = b * 256 + tid;
    float4 v = ((const float4*)x)[i];
    u16 o[4] = { f2b(v.x), f2b(v.y), f2b(v.z), f2b(v.w) };
    *(uint2*)&xb[(size_t)i * 4] = *(const uint2*)o;
    return;
  }
  b -= 5760;
  cvtT_tile(tile, wqT, Wq, 2880, 4096, b % 128, b / 128, tid);
}

// ---- prep2: WkT + WvT (1440 each) + bkv pack (4 blocks) ----
__global__ __launch_bounds__(256) void k_prep2(
    u16* __restrict__ wkvT, const float* __restrict__ Wk,
    const float* __restrict__ Wv, float* __restrict__ bkv,
    const float* __restrict__ bk, const float* __restrict__ bv){
  __shared__ float tile[32][33];
  int b = blockIdx.x, tid = threadIdx.x;
  if (b < 1440){ cvtT_tile(tile, wkvT, Wk, 2880, 512, b % 16, b / 16, tid); return; }
  b -= 1440;
  if (b < 1440){ cvtT_tile(tile, wkvT + (size_t)512 * 2880, Wv, 2880, 512, b % 16, b / 16, tid); return; }
  b -= 1440;
  int n = b * 256 + tid;
  if (n < 1024) bkv[n] = (n < 512) ? bk[n] : bv[n - 512];
}

// ---- prep3: WoT (11520 blocks) ----
__global__ __launch_bounds__(256) void k_prep3(
    u16* __restrict__ woT, const float* __restrict__ Wo){
  __shared__ float tile[32][33];
  int b = blockIdx.x, tid = threadIdx.x;
  cvtT_tile(tile, woT, Wo, 4096, 2880, b % 90, b / 90, tid);
}

// ======== 8-phase GEMM: BM=256, BN=128, BK=64, 512 thr (8 waves 4Mx2N) ========
// 3-buffer LDS ring (144KB), counted vmcnt(6), raw s_barrier, setprio,
// k-index XOR swizzle (read-side + inverse-swizzled global source).
// Optional fused RoPE on output columns (pairs via shfl_xor(1)).
template<int F32OUT, int ROPE>
__global__ __launch_bounds__(512, 1) void k_gemm8p(
    const u16* __restrict__ A, const u16* __restrict__ BT,
    const float* __restrict__ bias, void* __restrict__ C,
    const int* __restrict__ pos, int M, int N, int K, int ldc){
  __shared__ u16 lds[3][24576];   // per buf: A[256][64] @0, B[128][64] @16384

  const int tid = threadIdx.x;
  const int w = tid >> 6, l = tid & 63;
  const int wm = w >> 1, wn = w & 1;          // 4 x 2 waves
  const int lr = l & 15, lh = l >> 4;
  const int bid = blockIdx.x;
  const int mt = bid & 7, nt = bid >> 3;      // M>>8 == 8 always here
  const int m0 = mt << 8, n0 = nt << 7;

  const int srow = tid >> 3;                  // 0..63
  const int skc  = (tid & 7) << 3;            // 0,8,..,56
  const int ssw  = ((srow >> 2) & 3) << 4;    // stage-source k swizzle
  const int rsw  = ((lr >> 2) & 3) << 4;      // read-side k swizzle

  f32x4 acc[4][4];
#pragma unroll
  for (int mm = 0; mm < 4; mm++)
#pragma unroll
    for (int nn = 0; nn < 4; nn++){ acc[mm][nn][0]=0.f; acc[mm][nn][1]=0.f; acc[mm][nn][2]=0.f; acc[mm][nn][3]=0.f; }

#define STAGE_A(b, kt, c) \
  gload16(&A[(size_t)(m0 + (c)*64 + srow) * K + (kt) + (skc ^ ssw)], \
          (void*)&lds[b][((c)*64 + srow) * 64 + skc])
#define STAGE_B(b, kt, c) { \
  int _r = n0 + (c)*64 + srow; if (_r > N - 1) _r = N - 1; \
  gload16(&BT[(size_t)_r * K + (kt) + (skc ^ ssw)], \
          (void*)&lds[b][16384 + ((c)*64 + srow) * 64 + skc]); }

#define RD_A(dst, As, mm, kk) dst = *(const bf16x8*)&(As)[((wm<<6) + ((mm)<<4) + lr) * 64 + (((kk)<<5) + (lh<<3) ^ rsw)]
#define RD_B(dst, Bs, nn, kk) dst = *(const bf16x8*)&(Bs)[((wn<<6) + ((nn)<<4) + lr) * 64 + (((kk)<<5) + (lh<<3) ^ rsw)]

  const int NT = K >> 6;
  // prologue: stage tiles 0,1 into bufs 0,1 (6 loads each)
#pragma unroll
  for (int tt = 0; tt < 2; ++tt){
    int kt = tt << 6;
    STAGE_A(tt, kt, 0); STAGE_A(tt, kt, 1); STAGE_A(tt, kt, 2); STAGE_A(tt, kt, 3);
    STAGE_B(tt, kt, 0); STAGE_B(tt, kt, 1);
  }
  asm volatile("s_waitcnt vmcnt(6)" ::: "memory");   // tile 0 complete
  __builtin_amdgcn_s_barrier();

  int cb = 0;
  for (int t = 0; t < NT; ++t){
    const u16* As = &lds[cb][0];
    const u16* Bs = &lds[cb][16384];
    int sb = cb + 2; if (sb >= 3) sb -= 3;
    const int kt2 = (t + 2) << 6;
    const bool do_stage = (t + 2) < NT;
    bf16x8 af0k0, af0k1, af1k0, af1k1;
    bf16x8 bf0k0, bf0k1, bf1k0, bf1k1, bf2k0, bf2k1, bf3k0, bf3k1;

    // ---- phase 0: read a(m0,m1), b(n0,n1); stage A chunks 0,1; MFMA q(0,0)
    RD_A(af0k0, As, 0, 0); RD_A(af0k1, As, 0, 1);
    RD_A(af1k0, As, 1, 0); RD_A(af1k1, As, 1, 1);
    RD_B(bf0k0, Bs, 0, 0); RD_B(bf0k1, Bs, 0, 1);
    RD_B(bf1k0, Bs, 1, 0); RD_B(bf1k1, Bs, 1, 1);
    if (do_stage){ STAGE_A(sb, kt2, 0); STAGE_A(sb, kt2, 1); }
    __builtin_amdgcn_s_barrier();
    __builtin_amdgcn_s_setprio(1);
    acc[0][0] = MFMA16(af0k0, bf0k0, acc[0][0]); acc[0][0] = MFMA16(af0k1, bf0k1, acc[0][0]);
    acc[0][1] = MFMA16(af0k0, bf1k0, acc[0][1]); acc[0][1] = MFMA16(af0k1, bf1k1, acc[0][1]);
    acc[1][0] = MFMA16(af1k0, bf0k0, acc[1][0]); acc[1][0] = MFMA16(af1k1, bf0k1, acc[1][0]);
    acc[1][1] = MFMA16(af1k0, bf1k0, acc[1][1]); acc[1][1] = MFMA16(af1k1, bf1k1, acc[1][1]);
    __builtin_amdgcn_s_setprio(0);
    __builtin_amdgcn_s_barrier();

    // ---- phase 1: read b(n2,n3); stage A chunks 2,3; MFMA q(0,1)
    RD_B(bf2k0, Bs, 2, 0); RD_B(bf2k1, Bs, 2, 1);
    RD_B(bf3k0, Bs, 3, 0); RD_B(bf3k1, Bs, 3, 1);
    if (do_stage){ STAGE_A(sb, kt2, 2); STAGE_A(sb, kt2, 3); }
    __builtin_amdgcn_s_barrier();
    __builtin_amdgcn_s_setprio(1);
    acc[0][2] = MFMA16(af0k0, bf2k0, acc[0][2]); acc[0][2] = MFMA16(af0k1, bf2k1, acc[0][2]);
    acc[0][3] = MFMA16(af0k0, bf3k0, acc[0][3]); acc[0][3] = MFMA16(af0k1, bf3k1, acc[0][3]);
    acc[1][2] = MFMA16(af1k0, bf2k0, acc[1][2]); acc[1][2] = MFMA16(af1k1, bf2k1, acc[1][2]);
    acc[1][3] = MFMA16(af1k0, bf3k0, acc[1][3]); acc[1][3] = MFMA16(af1k1, bf3k1, acc[1][3]);
    __builtin_amdgcn_s_setprio(0);
    __builtin_amdgcn_s_barrier();

    // ---- phase 2: read a(m2,m3); stage B chunks 0,1; MFMA q(1,1)
    RD_A(af0k0, As, 2, 0); RD_A(af0k1, As, 2, 1);
    RD_A(af1k0, As, 3, 0); RD_A(af1k1, As, 3, 1);
    if (do_stage){ STAGE_B(sb, kt2, 0); STAGE_B(sb, kt2, 1); }
    __builtin_amdgcn_s_barrier();
    __builtin_amdgcn_s_setprio(1);
    acc[2][2] = MFMA16(af0k0, bf2k0, acc[2][2]); acc[2][2] = MFMA16(af0k1, bf2k1, acc[2][2]);
    acc[2][3] = MFMA16(af0k0, bf3k0, acc[2][3]); acc[2][3] = MFMA16(af0k1, bf3k1, acc[2][3]);
    acc[3][2] = MFMA16(af1k0, bf2k0, acc[3][2]); acc[3][2] = MFMA16(af1k1, bf2k1, acc[3][2]);
    acc[3][3] = MFMA16(af1k0, bf3k0, acc[3][3]); acc[3][3] = MFMA16(af1k1, bf3k1, acc[3][3]);
    __builtin_amdgcn_s_setprio(0);
    __builtin_amdgcn_s_barrier();

    // ---- phase 3: MFMA q(1,0) (reuse regs); iter-boundary wait
    __builtin_amdgcn_s_setprio(1);
    acc[2][0] = MFMA16(af0k0, bf0k0, acc[2][0]); acc[2][0] = MFMA16(af0k1, bf0k1, acc[2][0]);
    acc[2][1] = MFMA16(af0k0, bf1k0, acc[2][1]); acc[2][1] = MFMA16(af0k1, bf1k1, acc[2][1]);
    acc[3][0] = MFMA16(af1k0, bf0k0, acc[3][0]); acc[3][0] = MFMA16(af1k1, bf0k1, acc[3][0]);
    acc[3][1] = MFMA16(af1k0, bf1k0, acc[3][1]); acc[3][1] = MFMA16(af1k1, bf1k1, acc[3][1]);
    __builtin_amdgcn_s_setprio(0);
    if (do_stage) asm volatile("s_waitcnt vmcnt(6)" ::: "memory");  // next tile ready, t+2 in flight
    else          asm volatile("s_waitcnt vmcnt(0)" ::: "memory");  // tail drain
    __builtin_amdgcn_s_barrier();

    cb += 1; if (cb >= 3) cb -= 3;
  }

  // ---- epilogue ----
#pragma unroll
  for (int mm = 0; mm < 4; mm++){
    int grow = m0 + (wm << 6) + (mm << 4) + (lh << 2);
#pragma unroll
    for (int nn = 0; nn < 4; nn++){
      int gcol = n0 + (wn << 6) + (nn << 4) + lr;
      if (gcol < N){
        float bs = bias[gcol];
        if (ROPE){
          int ii = (gcol & 63) >> 1;
          float inv = exp2f(-0.53733146f * (float)ii);
          float sgn = (lr & 1) ? 1.f : -1.f;
#pragma unroll
          for (int r = 0; r < 4; r++){
            float v = acc[mm][nn][r] + bs;
            float ang = (float)pos[grow + r] * 0.03125f * inv;
            float s, c; __sincosf(ang, &s, &c);
            float p = __shfl_xor(v, 1);
            v = v * c + p * sgn * s;
            ((u16*)C)[(size_t)(grow + r) * ldc + gcol] = f2b(scrub(v, 1e9f));
          }
        } else {
#pragma unroll
          for (int r = 0; r < 4; r++){
            float v = scrub(acc[mm][nn][r] + bs, 1e9f);
            size_t off = (size_t)(grow + r) * ldc + gcol;
            if (F32OUT) ((float*)C)[off] = v;
            else        ((u16*)C)[off]   = f2b(v);
          }
        }
      }
    }
  }
#undef STAGE_A
#undef STAGE_B
#undef RD_A
#undef RD_B
}

// -------- 128x64 m97-structure GEMM (for the small KV projection) --------
template<int F32OUT, int ROPE>
__global__ __launch_bounds__(256) void k_gemm_bt64(
    const u16* __restrict__ A, const u16* __restrict__ BT,
    const float* __restrict__ bias, void* __restrict__ C,
    const int* __restrict__ pos, int M, int N, int K, int ldc){
  __shared__ u16 As[128 * 32];
  __shared__ u16 Bs[64 * 32];
  int mt_count = M >> 7;
  int bid = blockIdx.x;
  int mt = bid % mt_count, nt = bid / mt_count;
  int m0 = mt << 7, n0 = nt << 6;
  int tid = threadIdx.x;
  int w = tid >> 6, l = tid & 63;
  int wm = w >> 1, wn = w & 1;
  int lr = l & 15, lh = l >> 4;

  f32x4 acc[4][2];
#pragma unroll
  for (int m = 0; m < 4; m++)
#pragma unroll
    for (int n = 0; n < 2; n++){ acc[m][n][0]=0.f; acc[m][n][1]=0.f; acc[m][n][2]=0.f; acc[m][n][3]=0.f; }

  for (int kt = 0; kt < K; kt += 32){
#pragma unroll
    for (int it = 0; it < 2; ++it){
      int idx = it * 256 + tid;
      int row = idx >> 2, kc = (idx & 3) << 3;
      gload16(&A[(size_t)(m0 + row) * K + kt + kc], &As[idx * 8]);
    }
    {
      int row = tid >> 2, kc = (tid & 3) << 3;
      gload16(&BT[(size_t)(n0 + row) * K + kt + kc], &Bs[tid * 8]);
    }
    __syncthreads();

    bf16x8 af[4], bfr[2];
#pragma unroll
    for (int m = 0; m < 4; m++)
      af[m] = *(const bf16x8*)&As[(wm * 64 + m * 16 + lr) * 32 + (lh << 3)];
#pragma unroll
    for (int n = 0; n < 2; n++)
      bfr[n] = *(const bf16x8*)&Bs[(wn * 32 + n * 16 + lr) * 32 + (lh << 3)];
#pragma unroll
    for (int m = 0; m < 4; m++)
#pragma unroll
      for (int n = 0; n < 2; n++)
        acc[m][n] = MFMA16(af[m], bfr[n], acc[m][n]);
    __syncthreads();
  }

#pragma unroll
  for (int m = 0; m < 4; m++){
    int row = m0 + wm * 64 + m * 16 + (lh << 2);
#pragma unroll
    for (int n = 0; n < 2; n++){
      int col = n0 + wn * 32 + n * 16 + lr;
      float bs = bias[col];
      if (ROPE && col < 512){   // k-columns: wave-uniform branch
        int ii = (col & 63) >> 1;
        float inv = exp2f(-0.53733146f * (float)ii);
        float sgn = (lr & 1) ? 1.f : -1.f;
#pragma unroll
        for (int r = 0; r < 4; r++){
          float v = acc[m][n][r] + bs;
          float ang = (float)pos[row + r] * 0.03125f * inv;
          float s, c; __sincosf(ang, &s, &c);
          float p = __shfl_xor(v, 1);
          v = v * c + p * sgn * s;
          ((u16*)C)[(size_t)(row + r) * ldc + col] = f2b(scrub(v, 1e9f));
        }
      } else {
#pragma unroll
        for (int r = 0; r < 4; r++){
          float v = scrub(acc[m][n][r] + bs, 1e9f);
          size_t off = (size_t)(row + r) * ldc + col;
          if (F32OUT) ((float*)C)[off] = v;
          else        ((u16*)C)[off]   = f2b(v);
        }
      }
    }
  }
}

// ---------------- attention (unchanged, verified) ----------------
__global__ __launch_bounds__(256) void k_attn(
    const u16* __restrict__ qkv, const float* __restrict__ sink,
    u16* __restrict__ y, const int* __restrict__ slide_p,
    const int* __restrict__ win_p){
  __shared__ u16 Ks[64][72];
  __shared__ u16 VTs[64][72];
  __shared__ u16 Plds[4][32][72];

  int bid = blockIdx.x;
  int qt = bid & 7, h = (bid >> 3) & 63, b = bid >> 9;
  int t0 = qt << 7;
  int g = h >> 3;
  int kcol = 4096 + g * 64, vcol = 4608 + g * 64;
  int tid = threadIdx.x, w = tid >> 6, l = tid & 63;
  int lr = l & 15, lh = l >> 4;
  int win = (*slide_p) ? (*win_p) : (1 << 30);
  int tq0 = t0 + w * 32;

  bf16x8 qf[2][2];
#pragma unroll
  for (int m = 0; m < 2; m++)
#pragma unroll
    for (int kk = 0; kk < 2; kk++){
      int q = tq0 + m * 16 + lr;
      qf[m][kk] = *(const bf16x8*)&qkv[(size_t)(b * 1024 + q) * 5120 + h * 64 + kk * 32 + lh * 8];
    }

  float run_max[2] = {-1e30f, -1e30f};
  float run_sum[2] = {0.f, 0.f};
  f32x4 acc_o[4][2];
#pragma unroll
  for (int dt = 0; dt < 4; dt++)
#pragma unroll
    for (int m = 0; m < 2; m++){ acc_o[dt][m][0]=0.f; acc_o[dt][m][1]=0.f; acc_o[dt][m][2]=0.f; acc_o[dt][m][3]=0.f; }

  for (int c = 0; c < 4; c++){
    int key0 = t0 - 128 + c * 64;
#pragma unroll
    for (int it = 0; it < 2; ++it){
      int idx = it * 256 + tid;
      int key = idx >> 3, dd = (idx & 7) << 3;
      int gk = key0 + key;
      uint4 kq = make_uint4(0, 0, 0, 0);
      uint4 vq = make_uint4(0, 0, 0, 0);
      if (gk >= 0){
        size_t rb = (size_t)(b * 1024 + gk) * 5120;
        kq = *(const uint4*)&qkv[rb + kcol + dd];
        vq = *(const uint4*)&qkv[rb + vcol + dd];
      }
      *(uint4*)&Ks[key][dd] = kq;
      const u16* tv = (const u16*)&vq;
#pragma unroll
      for (int j = 0; j < 8; j++) VTs[dd + j][key] = tv[j];
    }
    __syncthreads();

    bool rel = (key0 + 63 >= tq0 - (win - 1)) && (key0 <= tq0 + 31);
    if (rel){
      f32x4 sacc[2][4];
#pragma unroll
      for (int m = 0; m < 2; m++)
#pragma unroll
        for (int n = 0; n < 4; n++){ sacc[m][n][0]=0.f; sacc[m][n][1]=0.f; sacc[m][n][2]=0.f; sacc[m][n][3]=0.f; }
#pragma unroll
      for (int kk = 0; kk < 2; kk++){
#pragma unroll
        for (int n = 0; n < 4; n++){
          bf16x8 kf = *(const bf16x8*)&Ks[n * 16 + lr][kk * 32 + lh * 8];
          sacc[0][n] = MFMA16(kf, qf[0][kk], sacc[0][n]);
          sacc[1][n] = MFMA16(kf, qf[1][kk], sacc[1][n]);
        }
      }
#pragma unroll
      for (int m = 0; m < 2; m++){
        int qrow = tq0 + m * 16 + lr;
        float cmax = -INFINITY;
#pragma unroll
        for (int n = 0; n < 4; n++)
#pragma unroll
          for (int r = 0; r < 4; r++){
            int key = key0 + n * 16 + lh * 4 + r;
            float s = scrub(sacc[m][n][r] * 0.125f, 1e30f);
            bool valid = (key >= 0) && (key <= qrow) && (qrow - key < win);
            s = valid ? s : -INFINITY;
            sacc[m][n][r] = s;
            cmax = fmaxf(cmax, s);
          }
        cmax = fmaxf(cmax, __shfl_xor(cmax, 16));
        cmax = fmaxf(cmax, __shfl_xor(cmax, 32));
        float mnew = fmaxf(run_max[m], cmax);
        float corr = __expf(run_max[m] - mnew);
        run_max[m] = mnew;
        float rsum = 0.f;
#pragma unroll
        for (int n = 0; n < 4; n++)
#pragma unroll
          for (int r = 0; r < 4; r++){
            float p = __expf(sacc[m][n][r] - mnew);
            sacc[m][n][r] = p;
            rsum += p;
          }
        rsum += __shfl_xor(rsum, 16);
        rsum += __shfl_xor(rsum, 32);
        run_sum[m] = run_sum[m] * corr + rsum;
#pragma unroll
        for (int dt = 0; dt < 4; dt++) acc_o[dt][m] *= corr;
#pragma unroll
        for (int n = 0; n < 4; n++)
#pragma unroll
          for (int r = 0; r < 4; r++)
            Plds[w][m * 16 + lr][n * 16 + lh * 4 + r] = f2b(sacc[m][n][r]);
      }
#pragma unroll
      for (int ks = 0; ks < 2; ks++){
        bf16x8 pb[2];
#pragma unroll
        for (int m = 0; m < 2; m++)
          pb[m] = *(const bf16x8*)&Plds[w][m * 16 + lr][ks * 32 + lh * 8];
#pragma unroll
        for (int dt = 0; dt < 4; dt++){
          bf16x8 vf = *(const bf16x8*)&VTs[dt * 16 + lr][ks * 32 + lh * 8];
          acc_o[dt][0] = MFMA16(vf, pb[0], acc_o[dt][0]);
          acc_o[dt][1] = MFMA16(vf, pb[1], acc_o[dt][1]);
        }
      }
    }
    __syncthreads();
  }

  float sk = sink[h];
  float osc[2];
#pragma unroll
  for (int m = 0; m < 2; m++){
    float Mf = fmaxf(run_max[m], sk);
    float t = __expf(run_max[m] - Mf);
    float denom = run_sum[m] * t + __expf(sk - Mf);
    osc[m] = t / denom;
  }
#pragma unroll
  for (int dt = 0; dt < 4; dt++)
#pragma unroll
    for (int m = 0; m < 2; m++)
#pragma unroll
      for (int r = 0; r < 4; r++){
        int d = dt * 16 + lh * 4 + r;
        int q = tq0 + m * 16 + lr;
        y[(size_t)(b * 1024 + q) * 4096 + h * 64 + d] = f2b(scrub(acc_o[dt][m][r] * osc[m], 1e9f));
      }
}

// ---------------- host ----------------
extern "C" void kernel_launch(void* const* d_in, const int* in_sizes, int n_in,
                              void* d_out, int out_size, void* d_ws, size_t ws_size,
                              hipStream_t stream){
  const float* x    = (const float*)d_in[0];
  const int*   pos  = (const int*)d_in[1];
  const float* Wq   = (const float*)d_in[3];
  const float* bq   = (const float*)d_in[4];
  const float* Wk   = (const float*)d_in[5];
  const float* bk   = (const float*)d_in[6];
  const float* Wv   = (const float*)d_in[7];
  const float* bv   = (const float*)d_in[8];
  const float* Wo   = (const float*)d_in[9];
  const float* bo   = (const float*)d_in[10];
  const float* sink = (const float*)d_in[11];
  const int* slide  = (const int*)d_in[12];
  const int* winp   = (const int*)d_in[13];
  float* out = (float*)d_out;

  // Workspace (61.35 MB peak, proven):
  char* ws = (char*)d_ws;
  u16*   xb   = (u16*)(ws + 0);
  u16*   ybuf = (u16*)(ws + 0);
  u16*   qkv  = (u16*)(ws + 16777216);
  u16*   wqT  = (u16*)(ws + 37748736);
  u16*   wkvT = (u16*)(ws + 37748736);
  u16*   woT  = (u16*)(ws + 37748736);
  float* bkv  = (float*)(ws + 61341696);

  // prep1: x->bf16 + WqT
  k_prep1<<<5760 + 11520, 256, 0, stream>>>(xb, x, wqT, Wq);
  // Q projection + fused RoPE: M=2048,N=4096,K=2880 -> 8x32 = 256 WGs
  k_gemm8p<0, 1><<<256, 512, 0, stream>>>(xb, wqT, bq, qkv, pos, 2048, 4096, 2880, 5120);
  // prep2: WkT+WvT+bkv
  k_prep2<<<1440 + 1440 + 4, 256, 0, stream>>>(wkvT, Wk, Wv, bkv, bk, bv);
  // KV projection + fused RoPE on k-cols: N=1024 -> 16x16 = 256 WGs
  k_gemm_bt64<0, 1><<<16 * 16, 256, 0, stream>>>(xb, wkvT, bkv, qkv + 4096, pos, 2048, 1024, 2880, 5120);
  // prep3: WoT
  k_prep3<<<11520, 256, 0, stream>>>(woT, Wo);
  // attention
  k_attn<<<1024, 256, 0, stream>>>(qkv, sink, ybuf, slide, winp);
  // output projection: M=2048,N=2880,K=4096 -> 8x23 = 184 WGs (fp32 out, ragged N)
  k_gemm8p<1, 0><<<184, 512, 0, stream>>>(ybuf, woT, bo, out, pos, 2048, 2880, 4096, 2880);
}

// Round 7
// 233.078 us; speedup vs baseline: 1.3472x; 1.0735x over previous
//
#include <hip/hip_runtime.h>

typedef unsigned short u16;
typedef __attribute__((ext_vector_type(8))) short bf16x8;
typedef __attribute__((ext_vector_type(4))) float f32x4;

#define MFMA16(a,b,c) __builtin_amdgcn_mfma_f32_16x16x32_bf16((a),(b),(c),0,0,0)

__device__ __forceinline__ float b2f(u16 u){
  unsigned v = ((unsigned)u) << 16; float f;
  __builtin_memcpy(&f, &v, 4); return f;
}
__device__ __forceinline__ u16 f2b(float f){
  unsigned v; __builtin_memcpy(&v, &f, 4);
  v += 0x7FFFu + ((v >> 16) & 1u);
  return (u16)(v >> 16);
}
__device__ __forceinline__ float scrub(float v, float lim){
  return fminf(fmaxf(v, -lim), lim);   // NaN-filtering clamp
}
__device__ __forceinline__ void gload16(const void* g, void* l){
  __builtin_amdgcn_global_load_lds(
      (const __attribute__((address_space(1))) unsigned int*)g,
      (__attribute__((address_space(3))) unsigned int*)l, 16, 0, 0);
}

// ---- convert+transpose tile helper: dst[c][r] = bf16(src[r][c]) ----
__device__ __forceinline__ void cvtT_tile(float (*tile)[33],
    u16* __restrict__ dst, const float* __restrict__ src,
    int rows, int cols, int bx, int by, int tid){
  int n0 = bx * 32, r0 = by * 32;
  int tx = tid & 31, ty = tid >> 5;
#pragma unroll
  for (int i = 0; i < 4; i++)
    tile[ty + i * 8][tx] = src[(size_t)(r0 + ty + i * 8) * cols + n0 + tx];
  __syncthreads();
#pragma unroll
  for (int i = 0; i < 4; i++)
    dst[(size_t)(n0 + ty + i * 8) * rows + r0 + tx] = f2b(tile[tx][ty + i * 8]);
}

// ---- prep1: x -> bf16 (5760 blocks) + WqT (11520 blocks) ----
__global__ __launch_bounds__(256) void k_prep1(
    u16* __restrict__ xb, const float* __restrict__ x,
    u16* __restrict__ wqT, const float* __restrict__ Wq){
  __shared__ float tile[32][33];
  int b = blockIdx.x, tid = threadIdx.x;
  if (b < 5760){
    int i = b * 256 + tid;
    float4 v = ((const float4*)x)[i];
    u16 o[4] = { f2b(v.x), f2b(v.y), f2b(v.z), f2b(v.w) };
    *(uint2*)&xb[(size_t)i * 4] = *(const uint2*)o;
    return;
  }
  b -= 5760;
  cvtT_tile(tile, wqT, Wq, 2880, 4096, b % 128, b / 128, tid);
}

// ---- prep2: WkT + WvT (1440 each) + bkv pack (4 blocks) ----
__global__ __launch_bounds__(256) void k_prep2(
    u16* __restrict__ wkvT, const float* __restrict__ Wk,
    const float* __restrict__ Wv, float* __restrict__ bkv,
    const float* __restrict__ bk, const float* __restrict__ bv){
  __shared__ float tile[32][33];
  int b = blockIdx.x, tid = threadIdx.x;
  if (b < 1440){ cvtT_tile(tile, wkvT, Wk, 2880, 512, b % 16, b / 16, tid); return; }
  b -= 1440;
  if (b < 1440){ cvtT_tile(tile, wkvT + (size_t)512 * 2880, Wv, 2880, 512, b % 16, b / 16, tid); return; }
  b -= 1440;
  int n = b * 256 + tid;
  if (n < 1024) bkv[n] = (n < 512) ? bk[n] : bv[n - 512];
}

// ---- prep3: WoT (11520 blocks) ----
__global__ __launch_bounds__(256) void k_prep3(
    u16* __restrict__ woT, const float* __restrict__ Wo){
  __shared__ float tile[32][33];
  int b = blockIdx.x, tid = threadIdx.x;
  cvtT_tile(tile, woT, Wo, 4096, 2880, b % 90, b / 90, tid);
}

// ======== 3-ring GEMM: BM=256, BN=128, BK=64, 512 thr (8 waves 4Mx2N) ========
// 3-buffer LDS ring (144KB): reads hit buf t, stages hit buf t+2 -> ONE
// barrier + counted vmcnt(6) per K-tile. 16B-granular k-XOR swizzle
// (inverse-swizzled global source + swizzled ds_read) -> 2-way (free).
template<int F32OUT, int ROPE>
__global__ __launch_bounds__(512, 1) void k_gemm8p(
    const u16* __restrict__ A, const u16* __restrict__ BT,
    const float* __restrict__ bias, void* __restrict__ C,
    const int* __restrict__ pos, int M, int N, int K, int ldc){
  __shared__ u16 lds[3][24576];   // per buf: A[256][64] @0, B[128][64] @16384

  const int tid = threadIdx.x;
  const int w = tid >> 6, l = tid & 63;
  const int wm = w >> 1, wn = w & 1;          // 4 x 2 waves
  const int lr = l & 15, lh = l >> 4;
  const int bid = blockIdx.x;
  const int mt = bid & 7, nt = bid >> 3;      // M>>8 == 8 always here
  const int m0 = mt << 8, n0 = nt << 7;

  const int srow = tid >> 3;                  // 0..63
  const int skc  = (tid & 7) << 3;            // 0,8,..,56 (elements)
  const int ssw  = (srow & 7) << 3;           // stage-source k swizzle (16B gran)
  const int rsw  = (lr & 7) << 3;             // read-side k swizzle

  f32x4 acc[4][4];
#pragma unroll
  for (int mm = 0; mm < 4; mm++)
#pragma unroll
    for (int nn = 0; nn < 4; nn++){ acc[mm][nn][0]=0.f; acc[mm][nn][1]=0.f; acc[mm][nn][2]=0.f; acc[mm][nn][3]=0.f; }

#define STAGE_A(b, kt, c) \
  gload16(&A[(size_t)(m0 + (c)*64 + srow) * K + (kt) + (skc ^ ssw)], \
          (void*)&lds[b][((c)*64 + srow) * 64 + skc])
#define STAGE_B(b, kt, c) { \
  int _r = n0 + (c)*64 + srow; if (_r > N - 1) _r = N - 1; \
  gload16(&BT[(size_t)_r * K + (kt) + (skc ^ ssw)], \
          (void*)&lds[b][16384 + ((c)*64 + srow) * 64 + skc]); }

#define RD_A(dst, As, mm, kk) dst = *(const bf16x8*)&(As)[((wm<<6) + ((mm)<<4) + lr) * 64 + ((((kk)<<5) + (lh<<3)) ^ rsw)]
#define RD_B(dst, Bs, nn, kk) dst = *(const bf16x8*)&(Bs)[((wn<<6) + ((nn)<<4) + lr) * 64 + ((((kk)<<5) + (lh<<3)) ^ rsw)]

  const int NT = K >> 6;
  // prologue: stage tiles 0,1 into bufs 0,1 (6 loads each)
#pragma unroll
  for (int tt = 0; tt < 2; ++tt){
    int kt = tt << 6;
    STAGE_A(tt, kt, 0); STAGE_A(tt, kt, 1); STAGE_A(tt, kt, 2); STAGE_A(tt, kt, 3);
    STAGE_B(tt, kt, 0); STAGE_B(tt, kt, 1);
  }
  asm volatile("s_waitcnt vmcnt(6)" ::: "memory");   // tile 0 complete
  __builtin_amdgcn_s_barrier();

  int cb = 0;
  for (int t = 0; t < NT; ++t){
    const u16* As = &lds[cb][0];
    const u16* Bs = &lds[cb][16384];
    int sb = cb + 2; if (sb >= 3) sb -= 3;
    const int kt2 = (t + 2) << 6;
    const bool do_stage = (t + 2) < NT;

    // issue next-next tile's loads early (hide under this tile's compute)
    if (do_stage){
      STAGE_A(sb, kt2, 0); STAGE_A(sb, kt2, 1); STAGE_A(sb, kt2, 2); STAGE_A(sb, kt2, 3);
      STAGE_B(sb, kt2, 0); STAGE_B(sb, kt2, 1);
    }

    bf16x8 a00,a01,a10,a11,a20,a21,a30,a31, b00,b01,b10,b11;
    RD_A(a00, As, 0, 0); RD_A(a01, As, 0, 1);
    RD_A(a10, As, 1, 0); RD_A(a11, As, 1, 1);
    RD_A(a20, As, 2, 0); RD_A(a21, As, 2, 1);
    RD_A(a30, As, 3, 0); RD_A(a31, As, 3, 1);
    RD_B(b00, Bs, 0, 0); RD_B(b01, Bs, 0, 1);
    RD_B(b10, Bs, 1, 0); RD_B(b11, Bs, 1, 1);
    __builtin_amdgcn_s_setprio(1);
    acc[0][0]=MFMA16(a00,b00,acc[0][0]); acc[0][0]=MFMA16(a01,b01,acc[0][0]);
    acc[1][0]=MFMA16(a10,b00,acc[1][0]); acc[1][0]=MFMA16(a11,b01,acc[1][0]);
    acc[2][0]=MFMA16(a20,b00,acc[2][0]); acc[2][0]=MFMA16(a21,b01,acc[2][0]);
    acc[3][0]=MFMA16(a30,b00,acc[3][0]); acc[3][0]=MFMA16(a31,b01,acc[3][0]);
    acc[0][1]=MFMA16(a00,b10,acc[0][1]); acc[0][1]=MFMA16(a01,b11,acc[0][1]);
    acc[1][1]=MFMA16(a10,b10,acc[1][1]); acc[1][1]=MFMA16(a11,b11,acc[1][1]);
    acc[2][1]=MFMA16(a20,b10,acc[2][1]); acc[2][1]=MFMA16(a21,b11,acc[2][1]);
    acc[3][1]=MFMA16(a30,b10,acc[3][1]); acc[3][1]=MFMA16(a31,b11,acc[3][1]);
    __builtin_amdgcn_s_setprio(0);

    RD_B(b00, Bs, 2, 0); RD_B(b01, Bs, 2, 1);
    RD_B(b10, Bs, 3, 0); RD_B(b11, Bs, 3, 1);
    __builtin_amdgcn_s_setprio(1);
    acc[0][2]=MFMA16(a00,b00,acc[0][2]); acc[0][2]=MFMA16(a01,b01,acc[0][2]);
    acc[1][2]=MFMA16(a10,b00,acc[1][2]); acc[1][2]=MFMA16(a11,b01,acc[1][2]);
    acc[2][2]=MFMA16(a20,b00,acc[2][2]); acc[2][2]=MFMA16(a21,b01,acc[2][2]);
    acc[3][2]=MFMA16(a30,b00,acc[3][2]); acc[3][2]=MFMA16(a31,b01,acc[3][2]);
    acc[0][3]=MFMA16(a00,b10,acc[0][3]); acc[0][3]=MFMA16(a01,b11,acc[0][3]);
    acc[1][3]=MFMA16(a10,b10,acc[1][3]); acc[1][3]=MFMA16(a11,b11,acc[1][3]);
    acc[2][3]=MFMA16(a20,b10,acc[2][3]); acc[2][3]=MFMA16(a21,b11,acc[2][3]);
    acc[3][3]=MFMA16(a30,b10,acc[3][3]); acc[3][3]=MFMA16(a31,b11,acc[3][3]);
    __builtin_amdgcn_s_setprio(0);

    // single sync point per K-tile: own t+1 loads drained, then block barrier
    if (do_stage) asm volatile("s_waitcnt vmcnt(6)" ::: "memory");
    else          asm volatile("s_waitcnt vmcnt(0)" ::: "memory");
    __builtin_amdgcn_s_barrier();

    cb += 1; if (cb >= 3) cb -= 3;
  }

  // ---- epilogue ----
#pragma unroll
  for (int mm = 0; mm < 4; mm++){
    int grow = m0 + (wm << 6) + (mm << 4) + (lh << 2);
#pragma unroll
    for (int nn = 0; nn < 4; nn++){
      int gcol = n0 + (wn << 6) + (nn << 4) + lr;
      if (gcol < N){
        float bs = bias[gcol];
        if (ROPE){
          int ii = (gcol & 63) >> 1;
          float inv = exp2f(-0.53733146f * (float)ii);
          float sgn = (lr & 1) ? 1.f : -1.f;
#pragma unroll
          for (int r = 0; r < 4; r++){
            float v = acc[mm][nn][r] + bs;
            float ang = (float)pos[grow + r] * 0.03125f * inv;
            float s, c; __sincosf(ang, &s, &c);
            float p = __shfl_xor(v, 1);
            v = v * c + p * sgn * s;
            ((u16*)C)[(size_t)(grow + r) * ldc + gcol] = f2b(scrub(v, 1e9f));
          }
        } else {
#pragma unroll
          for (int r = 0; r < 4; r++){
            float v = scrub(acc[mm][nn][r] + bs, 1e9f);
            size_t off = (size_t)(grow + r) * ldc + gcol;
            if (F32OUT) ((float*)C)[off] = v;
            else        ((u16*)C)[off]   = f2b(v);
          }
        }
      }
    }
  }
#undef STAGE_A
#undef STAGE_B
#undef RD_A
#undef RD_B
}

// -------- 128x64 m97-structure GEMM (for the small KV projection) --------
template<int F32OUT, int ROPE>
__global__ __launch_bounds__(256) void k_gemm_bt64(
    const u16* __restrict__ A, const u16* __restrict__ BT,
    const float* __restrict__ bias, void* __restrict__ C,
    const int* __restrict__ pos, int M, int N, int K, int ldc){
  __shared__ u16 As[128 * 32];
  __shared__ u16 Bs[64 * 32];
  int mt_count = M >> 7;
  int bid = blockIdx.x;
  int mt = bid % mt_count, nt = bid / mt_count;
  int m0 = mt << 7, n0 = nt << 6;
  int tid = threadIdx.x;
  int w = tid >> 6, l = tid & 63;
  int wm = w >> 1, wn = w & 1;
  int lr = l & 15, lh = l >> 4;

  f32x4 acc[4][2];
#pragma unroll
  for (int m = 0; m < 4; m++)
#pragma unroll
    for (int n = 0; n < 2; n++){ acc[m][n][0]=0.f; acc[m][n][1]=0.f; acc[m][n][2]=0.f; acc[m][n][3]=0.f; }

  for (int kt = 0; kt < K; kt += 32){
#pragma unroll
    for (int it = 0; it < 2; ++it){
      int idx = it * 256 + tid;
      int row = idx >> 2, kc = (idx & 3) << 3;
      gload16(&A[(size_t)(m0 + row) * K + kt + kc], &As[idx * 8]);
    }
    {
      int row = tid >> 2, kc = (tid & 3) << 3;
      gload16(&BT[(size_t)(n0 + row) * K + kt + kc], &Bs[tid * 8]);
    }
    __syncthreads();

    bf16x8 af[4], bfr[2];
#pragma unroll
    for (int m = 0; m < 4; m++)
      af[m] = *(const bf16x8*)&As[(wm * 64 + m * 16 + lr) * 32 + (lh << 3)];
#pragma unroll
    for (int n = 0; n < 2; n++)
      bfr[n] = *(const bf16x8*)&Bs[(wn * 32 + n * 16 + lr) * 32 + (lh << 3)];
#pragma unroll
    for (int m = 0; m < 4; m++)
#pragma unroll
      for (int n = 0; n < 2; n++)
        acc[m][n] = MFMA16(af[m], bfr[n], acc[m][n]);
    __syncthreads();
  }

#pragma unroll
  for (int m = 0; m < 4; m++){
    int row = m0 + wm * 64 + m * 16 + (lh << 2);
#pragma unroll
    for (int n = 0; n < 2; n++){
      int col = n0 + wn * 32 + n * 16 + lr;
      float bs = bias[col];
      if (ROPE && col < 512){   // k-columns: wave-uniform branch
        int ii = (col & 63) >> 1;
        float inv = exp2f(-0.53733146f * (float)ii);
        float sgn = (lr & 1) ? 1.f : -1.f;
#pragma unroll
        for (int r = 0; r < 4; r++){
          float v = acc[m][n][r] + bs;
          float ang = (float)pos[row + r] * 0.03125f * inv;
          float s, c; __sincosf(ang, &s, &c);
          float p = __shfl_xor(v, 1);
          v = v * c + p * sgn * s;
          ((u16*)C)[(size_t)(row + r) * ldc + col] = f2b(scrub(v, 1e9f));
        }
      } else {
#pragma unroll
        for (int r = 0; r < 4; r++){
          float v = scrub(acc[m][n][r] + bs, 1e9f);
          size_t off = (size_t)(row + r) * ldc + col;
          if (F32OUT) ((float*)C)[off] = v;
          else        ((u16*)C)[off]   = f2b(v);
        }
      }
    }
  }
}

// ---------------- attention (unchanged, verified) ----------------
__global__ __launch_bounds__(256) void k_attn(
    const u16* __restrict__ qkv, const float* __restrict__ sink,
    u16* __restrict__ y, const int* __restrict__ slide_p,
    const int* __restrict__ win_p){
  __shared__ u16 Ks[64][72];
  __shared__ u16 VTs[64][72];
  __shared__ u16 Plds[4][32][72];

  int bid = blockIdx.x;
  int qt = bid & 7, h = (bid >> 3) & 63, b = bid >> 9;
  int t0 = qt << 7;
  int g = h >> 3;
  int kcol = 4096 + g * 64, vcol = 4608 + g * 64;
  int tid = threadIdx.x, w = tid >> 6, l = tid & 63;
  int lr = l & 15, lh = l >> 4;
  int win = (*slide_p) ? (*win_p) : (1 << 30);
  int tq0 = t0 + w * 32;

  bf16x8 qf[2][2];
#pragma unroll
  for (int m = 0; m < 2; m++)
#pragma unroll
    for (int kk = 0; kk < 2; kk++){
      int q = tq0 + m * 16 + lr;
      qf[m][kk] = *(const bf16x8*)&qkv[(size_t)(b * 1024 + q) * 5120 + h * 64 + kk * 32 + lh * 8];
    }

  float run_max[2] = {-1e30f, -1e30f};
  float run_sum[2] = {0.f, 0.f};
  f32x4 acc_o[4][2];
#pragma unroll
  for (int dt = 0; dt < 4; dt++)
#pragma unroll
    for (int m = 0; m < 2; m++){ acc_o[dt][m][0]=0.f; acc_o[dt][m][1]=0.f; acc_o[dt][m][2]=0.f; acc_o[dt][m][3]=0.f; }

  for (int c = 0; c < 4; c++){
    int key0 = t0 - 128 + c * 64;
#pragma unroll
    for (int it = 0; it < 2; ++it){
      int idx = it * 256 + tid;
      int key = idx >> 3, dd = (idx & 7) << 3;
      int gk = key0 + key;
      uint4 kq = make_uint4(0, 0, 0, 0);
      uint4 vq = make_uint4(0, 0, 0, 0);
      if (gk >= 0){
        size_t rb = (size_t)(b * 1024 + gk) * 5120;
        kq = *(const uint4*)&qkv[rb + kcol + dd];
        vq = *(const uint4*)&qkv[rb + vcol + dd];
      }
      *(uint4*)&Ks[key][dd] = kq;
      const u16* tv = (const u16*)&vq;
#pragma unroll
      for (int j = 0; j < 8; j++) VTs[dd + j][key] = tv[j];
    }
    __syncthreads();

    bool rel = (key0 + 63 >= tq0 - (win - 1)) && (key0 <= tq0 + 31);
    if (rel){
      f32x4 sacc[2][4];
#pragma unroll
      for (int m = 0; m < 2; m++)
#pragma unroll
        for (int n = 0; n < 4; n++){ sacc[m][n][0]=0.f; sacc[m][n][1]=0.f; sacc[m][n][2]=0.f; sacc[m][n][3]=0.f; }
#pragma unroll
      for (int kk = 0; kk < 2; kk++){
#pragma unroll
        for (int n = 0; n < 4; n++){
          bf16x8 kf = *(const bf16x8*)&Ks[n * 16 + lr][kk * 32 + lh * 8];
          sacc[0][n] = MFMA16(kf, qf[0][kk], sacc[0][n]);
          sacc[1][n] = MFMA16(kf, qf[1][kk], sacc[1][n]);
        }
      }
#pragma unroll
      for (int m = 0; m < 2; m++){
        int qrow = tq0 + m * 16 + lr;
        float cmax = -INFINITY;
#pragma unroll
        for (int n = 0; n < 4; n++)
#pragma unroll
          for (int r = 0; r < 4; r++){
            int key = key0 + n * 16 + lh * 4 + r;
            float s = scrub(sacc[m][n][r] * 0.125f, 1e30f);
            bool valid = (key >= 0) && (key <= qrow) && (qrow - key < win);
            s = valid ? s : -INFINITY;
            sacc[m][n][r] = s;
            cmax = fmaxf(cmax, s);
          }
        cmax = fmaxf(cmax, __shfl_xor(cmax, 16));
        cmax = fmaxf(cmax, __shfl_xor(cmax, 32));
        float mnew = fmaxf(run_max[m], cmax);
        float corr = __expf(run_max[m] - mnew);
        run_max[m] = mnew;
        float rsum = 0.f;
#pragma unroll
        for (int n = 0; n < 4; n++)
#pragma unroll
          for (int r = 0; r < 4; r++){
            float p = __expf(sacc[m][n][r] - mnew);
            sacc[m][n][r] = p;
            rsum += p;
          }
        rsum += __shfl_xor(rsum, 16);
        rsum += __shfl_xor(rsum, 32);
        run_sum[m] = run_sum[m] * corr + rsum;
#pragma unroll
        for (int dt = 0; dt < 4; dt++) acc_o[dt][m] *= corr;
#pragma unroll
        for (int n = 0; n < 4; n++)
#pragma unroll
          for (int r = 0; r < 4; r++)
            Plds[w][m * 16 + lr][n * 16 + lh * 4 + r] = f2b(sacc[m][n][r]);
      }
#pragma unroll
      for (int ks = 0; ks < 2; ks++){
        bf16x8 pb[2];
#pragma unroll
        for (int m = 0; m < 2; m++)
          pb[m] = *(const bf16x8*)&Plds[w][m * 16 + lr][ks * 32 + lh * 8];
#pragma unroll
        for (int dt = 0; dt < 4; dt++){
          bf16x8 vf = *(const bf16x8*)&VTs[dt * 16 + lr][ks * 32 + lh * 8];
          acc_o[dt][0] = MFMA16(vf, pb[0], acc_o[dt][0]);
          acc_o[dt][1] = MFMA16(vf, pb[1], acc_o[dt][1]);
        }
      }
    }
    __syncthreads();
  }

  float sk = sink[h];
  float osc[2];
#pragma unroll
  for (int m = 0; m < 2; m++){
    float Mf = fmaxf(run_max[m], sk);
    float t = __expf(run_max[m] - Mf);
    float denom = run_sum[m] * t + __expf(sk - Mf);
    osc[m] = t / denom;
  }
#pragma unroll
  for (int dt = 0; dt < 4; dt++)
#pragma unroll
    for (int m = 0; m < 2; m++)
#pragma unroll
      for (int r = 0; r < 4; r++){
        int d = dt * 16 + lh * 4 + r;
        int q = tq0 + m * 16 + lr;
        y[(size_t)(b * 1024 + q) * 4096 + h * 64 + d] = f2b(scrub(acc_o[dt][m][r] * osc[m], 1e9f));
      }
}

// ---------------- host ----------------
extern "C" void kernel_launch(void* const* d_in, const int* in_sizes, int n_in,
                              void* d_out, int out_size, void* d_ws, size_t ws_size,
                              hipStream_t stream){
  const float* x    = (const float*)d_in[0];
  const int*   pos  = (const int*)d_in[1];
  const float* Wq   = (const float*)d_in[3];
  const float* bq   = (const float*)d_in[4];
  const float* Wk   = (const float*)d_in[5];
  const float* bk   = (const float*)d_in[6];
  const float* Wv   = (const float*)d_in[7];
  const float* bv   = (const float*)d_in[8];
  const float* Wo   = (const float*)d_in[9];
  const float* bo   = (const float*)d_in[10];
  const float* sink = (const float*)d_in[11];
  const int* slide  = (const int*)d_in[12];
  const int* winp   = (const int*)d_in[13];
  float* out = (float*)d_out;

  // Workspace (61.35 MB peak, proven):
  char* ws = (char*)d_ws;
  u16*   xb   = (u16*)(ws + 0);
  u16*   ybuf = (u16*)(ws + 0);
  u16*   qkv  = (u16*)(ws + 16777216);
  u16*   wqT  = (u16*)(ws + 37748736);
  u16*   wkvT = (u16*)(ws + 37748736);
  u16*   woT  = (u16*)(ws + 37748736);
  float* bkv  = (float*)(ws + 61341696);

  // prep1: x->bf16 + WqT
  k_prep1<<<5760 + 11520, 256, 0, stream>>>(xb, x, wqT, Wq);
  // Q projection + fused RoPE: M=2048,N=4096,K=2880 -> 8x32 = 256 WGs
  k_gemm8p<0, 1><<<256, 512, 0, stream>>>(xb, wqT, bq, qkv, pos, 2048, 4096, 2880, 5120);
  // prep2: WkT+WvT+bkv
  k_prep2<<<1440 + 1440 + 4, 256, 0, stream>>>(wkvT, Wk, Wv, bkv, bk, bv);
  // KV projection + fused RoPE on k-cols: N=1024 -> 16x16 = 256 WGs
  k_gemm_bt64<0, 1><<<16 * 16, 256, 0, stream>>>(xb, wkvT, bkv, qkv + 4096, pos, 2048, 1024, 2880, 5120);
  // prep3: WoT
  k_prep3<<<11520, 256, 0, stream>>>(woT, Wo);
  // attention
  k_attn<<<1024, 256, 0, stream>>>(qkv, sink, ybuf, slide, winp);
  // output projection: M=2048,N=2880,K=4096 -> 8x23 = 184 WGs (fp32 out, ragged N)
  k_gemm8p<1, 0><<<184, 512, 0, stream>>>(ybuf, woT, bo, out, pos, 2048, 2880, 4096, 2880);
}

// Round 8
// 229.005 us; speedup vs baseline: 1.3712x; 1.0178x over previous
//
#include <hip/hip_runtime.h>

typedef unsigned short u16;
typedef __attribute__((ext_vector_type(8))) short bf16x8;
typedef __attribute__((ext_vector_type(4))) float f32x4;

#define MFMA16(a,b,c) __builtin_amdgcn_mfma_f32_16x16x32_bf16((a),(b),(c),0,0,0)

__device__ __forceinline__ float b2f(u16 u){
  unsigned v = ((unsigned)u) << 16; float f;
  __builtin_memcpy(&f, &v, 4); return f;
}
__device__ __forceinline__ u16 f2b(float f){
  unsigned v; __builtin_memcpy(&v, &f, 4);
  v += 0x7FFFu + ((v >> 16) & 1u);
  return (u16)(v >> 16);
}
__device__ __forceinline__ float scrub(float v, float lim){
  return fminf(fmaxf(v, -lim), lim);   // NaN-filtering clamp
}
__device__ __forceinline__ void gload16(const void* g, void* l){
  __builtin_amdgcn_global_load_lds(
      (const __attribute__((address_space(1))) unsigned int*)g,
      (__attribute__((address_space(3))) unsigned int*)l, 16, 0, 0);
}

// ---- convert+transpose tile helper: dst[c][r] = bf16(src[r][c]) ----
__device__ __forceinline__ void cvtT_tile(float (*tile)[33],
    u16* __restrict__ dst, const float* __restrict__ src,
    int rows, int cols, int bx, int by, int tid){
  int n0 = bx * 32, r0 = by * 32;
  int tx = tid & 31, ty = tid >> 5;
#pragma unroll
  for (int i = 0; i < 4; i++)
    tile[ty + i * 8][tx] = src[(size_t)(r0 + ty + i * 8) * cols + n0 + tx];
  __syncthreads();
#pragma unroll
  for (int i = 0; i < 4; i++)
    dst[(size_t)(n0 + ty + i * 8) * rows + r0 + tx] = f2b(tile[tx][ty + i * 8]);
}

// ---- prep1: x -> bf16 (5760 blocks) + WqT (11520 blocks) ----
__global__ __launch_bounds__(256) void k_prep1(
    u16* __restrict__ xb, const float* __restrict__ x,
    u16* __restrict__ wqT, const float* __restrict__ Wq){
  __shared__ float tile[32][33];
  int b = blockIdx.x, tid = threadIdx.x;
  if (b < 5760){
    int i = b * 256 + tid;
    float4 v = ((const float4*)x)[i];
    u16 o[4] = { f2b(v.x), f2b(v.y), f2b(v.z), f2b(v.w) };
    *(uint2*)&xb[(size_t)i * 4] = *(const uint2*)o;
    return;
  }
  b -= 5760;
  cvtT_tile(tile, wqT, Wq, 2880, 4096, b % 128, b / 128, tid);
}

// ---- prep2: WkT + WvT (1440 each) + bkv pack (4 blocks) ----
__global__ __launch_bounds__(256) void k_prep2(
    u16* __restrict__ wkvT, const float* __restrict__ Wk,
    const float* __restrict__ Wv, float* __restrict__ bkv,
    const float* __restrict__ bk, const float* __restrict__ bv){
  __shared__ float tile[32][33];
  int b = blockIdx.x, tid = threadIdx.x;
  if (b < 1440){ cvtT_tile(tile, wkvT, Wk, 2880, 512, b % 16, b / 16, tid); return; }
  b -= 1440;
  if (b < 1440){ cvtT_tile(tile, wkvT + (size_t)512 * 2880, Wv, 2880, 512, b % 16, b / 16, tid); return; }
  b -= 1440;
  int n = b * 256 + tid;
  if (n < 1024) bkv[n] = (n < 512) ? bk[n] : bv[n - 512];
}

// ---- prep3: WoT (11520 blocks) ----
__global__ __launch_bounds__(256) void k_prep3(
    u16* __restrict__ woT, const float* __restrict__ Wo){
  __shared__ float tile[32][33];
  int b = blockIdx.x, tid = threadIdx.x;
  cvtT_tile(tile, woT, Wo, 4096, 2880, b % 90, b / 90, tid);
}

// ======== 3-ring GEMM: BM=256, BN=128, BK=64, 512 thr (8 waves 4Mx2N) ========
// 3-buffer LDS ring: reads hit buf t, stages hit buf t+2 -> ONE barrier +
// counted vmcnt(6) per K-tile. 16B k-XOR swizzle (2-way, free).
// MFMA clusters ordered k0-slice then k1-slice (dep dist 8); stage loads
// spread in 3 pairs across the tile body (continuous queue feed).
template<int F32OUT, int ROPE>
__global__ __launch_bounds__(512, 1) void k_gemm8p(
    const u16* __restrict__ A, const u16* __restrict__ BT,
    const float* __restrict__ bias, void* __restrict__ C,
    const int* __restrict__ pos, int M, int N, int K, int ldc){
  __shared__ u16 lds[3][24576];   // per buf: A[256][64] @0, B[128][64] @16384

  const int tid = threadIdx.x;
  const int w = tid >> 6, l = tid & 63;
  const int wm = w >> 1, wn = w & 1;          // 4 x 2 waves
  const int lr = l & 15, lh = l >> 4;
  const int bid = blockIdx.x;
  const int mt = bid & 7, nt = bid >> 3;      // M>>8 == 8 always here
  const int m0 = mt << 8, n0 = nt << 7;

  const int srow = tid >> 3;                  // 0..63
  const int skc  = (tid & 7) << 3;            // 0,8,..,56 (elements)
  const int ssw  = (srow & 7) << 3;           // stage-source k swizzle (16B gran)
  const int rsw  = (lr & 7) << 3;             // read-side k swizzle

  f32x4 acc[4][4];
#pragma unroll
  for (int mm = 0; mm < 4; mm++)
#pragma unroll
    for (int nn = 0; nn < 4; nn++){ acc[mm][nn][0]=0.f; acc[mm][nn][1]=0.f; acc[mm][nn][2]=0.f; acc[mm][nn][3]=0.f; }

#define STAGE_A(b, kt, c) \
  gload16(&A[(size_t)(m0 + (c)*64 + srow) * K + (kt) + (skc ^ ssw)], \
          (void*)&lds[b][((c)*64 + srow) * 64 + skc])
#define STAGE_B(b, kt, c) { \
  int _r = n0 + (c)*64 + srow; if (_r > N - 1) _r = N - 1; \
  gload16(&BT[(size_t)_r * K + (kt) + (skc ^ ssw)], \
          (void*)&lds[b][16384 + ((c)*64 + srow) * 64 + skc]); }

#define RD_A(dst, As, mm, kk) dst = *(const bf16x8*)&(As)[((wm<<6) + ((mm)<<4) + lr) * 64 + ((((kk)<<5) + (lh<<3)) ^ rsw)]
#define RD_B(dst, Bs, nn, kk) dst = *(const bf16x8*)&(Bs)[((wn<<6) + ((nn)<<4) + lr) * 64 + ((((kk)<<5) + (lh<<3)) ^ rsw)]

  const int NT = K >> 6;
  // prologue: stage tiles 0,1 into bufs 0,1 (6 loads each)
#pragma unroll
  for (int tt = 0; tt < 2; ++tt){
    int kt = tt << 6;
    STAGE_A(tt, kt, 0); STAGE_A(tt, kt, 1); STAGE_A(tt, kt, 2); STAGE_A(tt, kt, 3);
    STAGE_B(tt, kt, 0); STAGE_B(tt, kt, 1);
  }
  asm volatile("s_waitcnt vmcnt(6)" ::: "memory");   // tile 0 complete
  __builtin_amdgcn_s_barrier();

  int cb = 0;
  for (int t = 0; t < NT; ++t){
    const u16* As = &lds[cb][0];
    const u16* Bs = &lds[cb][16384];
    int sb = cb + 2; if (sb >= 3) sb -= 3;
    const int kt2 = (t + 2) << 6;
    const bool do_stage = (t + 2) < NT;

    bf16x8 a00,a01,a10,a11,a20,a21,a30,a31, b00,b01,b10,b11;
    RD_A(a00, As, 0, 0); RD_A(a01, As, 0, 1);
    RD_A(a10, As, 1, 0); RD_A(a11, As, 1, 1);
    RD_A(a20, As, 2, 0); RD_A(a21, As, 2, 1);
    RD_A(a30, As, 3, 0); RD_A(a31, As, 3, 1);
    RD_B(b00, Bs, 0, 0); RD_B(b01, Bs, 0, 1);
    RD_B(b10, Bs, 1, 0); RD_B(b11, Bs, 1, 1);
    if (do_stage){ STAGE_A(sb, kt2, 0); STAGE_A(sb, kt2, 1); }
    __builtin_amdgcn_s_setprio(1);
    // cluster 1: k0 slice (8 independent), then k1 slice (dep dist 8)
    acc[0][0]=MFMA16(a00,b00,acc[0][0]);
    acc[1][0]=MFMA16(a10,b00,acc[1][0]);
    acc[2][0]=MFMA16(a20,b00,acc[2][0]);
    acc[3][0]=MFMA16(a30,b00,acc[3][0]);
    acc[0][1]=MFMA16(a00,b10,acc[0][1]);
    acc[1][1]=MFMA16(a10,b10,acc[1][1]);
    acc[2][1]=MFMA16(a20,b10,acc[2][1]);
    acc[3][1]=MFMA16(a30,b10,acc[3][1]);
    acc[0][0]=MFMA16(a01,b01,acc[0][0]);
    acc[1][0]=MFMA16(a11,b01,acc[1][0]);
    acc[2][0]=MFMA16(a21,b01,acc[2][0]);
    acc[3][0]=MFMA16(a31,b01,acc[3][0]);
    acc[0][1]=MFMA16(a01,b11,acc[0][1]);
    acc[1][1]=MFMA16(a11,b11,acc[1][1]);
    acc[2][1]=MFMA16(a21,b11,acc[2][1]);
    acc[3][1]=MFMA16(a31,b11,acc[3][1]);
    __builtin_amdgcn_s_setprio(0);

    RD_B(b00, Bs, 2, 0); RD_B(b01, Bs, 2, 1);
    RD_B(b10, Bs, 3, 0); RD_B(b11, Bs, 3, 1);
    if (do_stage){ STAGE_A(sb, kt2, 2); STAGE_A(sb, kt2, 3); }
    __builtin_amdgcn_s_setprio(1);
    // cluster 2: k0 slice, then k1 slice
    acc[0][2]=MFMA16(a00,b00,acc[0][2]);
    acc[1][2]=MFMA16(a10,b00,acc[1][2]);
    acc[2][2]=MFMA16(a20,b00,acc[2][2]);
    acc[3][2]=MFMA16(a30,b00,acc[3][2]);
    acc[0][3]=MFMA16(a00,b10,acc[0][3]);
    acc[1][3]=MFMA16(a10,b10,acc[1][3]);
    acc[2][3]=MFMA16(a20,b10,acc[2][3]);
    acc[3][3]=MFMA16(a30,b10,acc[3][3]);
    acc[0][2]=MFMA16(a01,b01,acc[0][2]);
    acc[1][2]=MFMA16(a11,b01,acc[1][2]);
    acc[2][2]=MFMA16(a21,b01,acc[2][2]);
    acc[3][2]=MFMA16(a31,b01,acc[3][2]);
    acc[0][3]=MFMA16(a01,b11,acc[0][3]);
    acc[1][3]=MFMA16(a11,b11,acc[1][3]);
    acc[2][3]=MFMA16(a21,b11,acc[2][3]);
    acc[3][3]=MFMA16(a31,b11,acc[3][3]);
    __builtin_amdgcn_s_setprio(0);

    if (do_stage){ STAGE_B(sb, kt2, 0); STAGE_B(sb, kt2, 1); }

    // single sync point per K-tile: own t+1 loads drained, then block barrier
    if (do_stage) asm volatile("s_waitcnt vmcnt(6)" ::: "memory");
    else          asm volatile("s_waitcnt vmcnt(0)" ::: "memory");
    __builtin_amdgcn_s_barrier();

    cb += 1; if (cb >= 3) cb -= 3;
  }

  // ---- epilogue ----
#pragma unroll
  for (int mm = 0; mm < 4; mm++){
    int grow = m0 + (wm << 6) + (mm << 4) + (lh << 2);
#pragma unroll
    for (int nn = 0; nn < 4; nn++){
      int gcol = n0 + (wn << 6) + (nn << 4) + lr;
      if (gcol < N){
        float bs = bias[gcol];
        if (ROPE){
          int ii = (gcol & 63) >> 1;
          float inv = exp2f(-0.53733146f * (float)ii);
          float sgn = (lr & 1) ? 1.f : -1.f;
#pragma unroll
          for (int r = 0; r < 4; r++){
            float v = acc[mm][nn][r] + bs;
            float ang = (float)pos[grow + r] * 0.03125f * inv;
            float s, c; __sincosf(ang, &s, &c);
            float p = __shfl_xor(v, 1);
            v = v * c + p * sgn * s;
            ((u16*)C)[(size_t)(grow + r) * ldc + gcol] = f2b(scrub(v, 1e9f));
          }
        } else {
#pragma unroll
          for (int r = 0; r < 4; r++){
            float v = scrub(acc[mm][nn][r] + bs, 1e9f);
            size_t off = (size_t)(grow + r) * ldc + gcol;
            if (F32OUT) ((float*)C)[off] = v;
            else        ((u16*)C)[off]   = f2b(v);
          }
        }
      }
    }
  }
#undef STAGE_A
#undef STAGE_B
#undef RD_A
#undef RD_B
}

// -------- 128x64 m97-structure GEMM (for the small KV projection) --------
template<int F32OUT, int ROPE>
__global__ __launch_bounds__(256) void k_gemm_bt64(
    const u16* __restrict__ A, const u16* __restrict__ BT,
    const float* __restrict__ bias, void* __restrict__ C,
    const int* __restrict__ pos, int M, int N, int K, int ldc){
  __shared__ u16 As[128 * 32];
  __shared__ u16 Bs[64 * 32];
  int mt_count = M >> 7;
  int bid = blockIdx.x;
  int mt = bid % mt_count, nt = bid / mt_count;
  int m0 = mt << 7, n0 = nt << 6;
  int tid = threadIdx.x;
  int w = tid >> 6, l = tid & 63;
  int wm = w >> 1, wn = w & 1;
  int lr = l & 15, lh = l >> 4;

  f32x4 acc[4][2];
#pragma unroll
  for (int m = 0; m < 4; m++)
#pragma unroll
    for (int n = 0; n < 2; n++){ acc[m][n][0]=0.f; acc[m][n][1]=0.f; acc[m][n][2]=0.f; acc[m][n][3]=0.f; }

  for (int kt = 0; kt < K; kt += 32){
#pragma unroll
    for (int it = 0; it < 2; ++it){
      int idx = it * 256 + tid;
      int row = idx >> 2, kc = (idx & 3) << 3;
      gload16(&A[(size_t)(m0 + row) * K + kt + kc], &As[idx * 8]);
    }
    {
      int row = tid >> 2, kc = (tid & 3) << 3;
      gload16(&BT[(size_t)(n0 + row) * K + kt + kc], &Bs[tid * 8]);
    }
    __syncthreads();

    bf16x8 af[4], bfr[2];
#pragma unroll
    for (int m = 0; m < 4; m++)
      af[m] = *(const bf16x8*)&As[(wm * 64 + m * 16 + lr) * 32 + (lh << 3)];
#pragma unroll
    for (int n = 0; n < 2; n++)
      bfr[n] = *(const bf16x8*)&Bs[(wn * 32 + n * 16 + lr) * 32 + (lh << 3)];
#pragma unroll
    for (int m = 0; m < 4; m++)
#pragma unroll
      for (int n = 0; n < 2; n++)
        acc[m][n] = MFMA16(af[m], bfr[n], acc[m][n]);
    __syncthreads();
  }

#pragma unroll
  for (int m = 0; m < 4; m++){
    int row = m0 + wm * 64 + m * 16 + (lh << 2);
#pragma unroll
    for (int n = 0; n < 2; n++){
      int col = n0 + wn * 32 + n * 16 + lr;
      float bs = bias[col];
      if (ROPE && col < 512){   // k-columns: wave-uniform branch
        int ii = (col & 63) >> 1;
        float inv = exp2f(-0.53733146f * (float)ii);
        float sgn = (lr & 1) ? 1.f : -1.f;
#pragma unroll
        for (int r = 0; r < 4; r++){
          float v = acc[m][n][r] + bs;
          float ang = (float)pos[row + r] * 0.03125f * inv;
          float s, c; __sincosf(ang, &s, &c);
          float p = __shfl_xor(v, 1);
          v = v * c + p * sgn * s;
          ((u16*)C)[(size_t)(row + r) * ldc + col] = f2b(scrub(v, 1e9f));
        }
      } else {
#pragma unroll
        for (int r = 0; r < 4; r++){
          float v = scrub(acc[m][n][r] + bs, 1e9f);
          size_t off = (size_t)(row + r) * ldc + col;
          if (F32OUT) ((float*)C)[off] = v;
          else        ((u16*)C)[off]   = f2b(v);
        }
      }
    }
  }
}

// ---------------- attention (unchanged, verified) ----------------
__global__ __launch_bounds__(256) void k_attn(
    const u16* __restrict__ qkv, const float* __restrict__ sink,
    u16* __restrict__ y, const int* __restrict__ slide_p,
    const int* __restrict__ win_p){
  __shared__ u16 Ks[64][72];
  __shared__ u16 VTs[64][72];
  __shared__ u16 Plds[4][32][72];

  int bid = blockIdx.x;
  int qt = bid & 7, h = (bid >> 3) & 63, b = bid >> 9;
  int t0 = qt << 7;
  int g = h >> 3;
  int kcol = 4096 + g * 64, vcol = 4608 + g * 64;
  int tid = threadIdx.x, w = tid >> 6, l = tid & 63;
  int lr = l & 15, lh = l >> 4;
  int win = (*slide_p) ? (*win_p) : (1 << 30);
  int tq0 = t0 + w * 32;

  bf16x8 qf[2][2];
#pragma unroll
  for (int m = 0; m < 2; m++)
#pragma unroll
    for (int kk = 0; kk < 2; kk++){
      int q = tq0 + m * 16 + lr;
      qf[m][kk] = *(const bf16x8*)&qkv[(size_t)(b * 1024 + q) * 5120 + h * 64 + kk * 32 + lh * 8];
    }

  float run_max[2] = {-1e30f, -1e30f};
  float run_sum[2] = {0.f, 0.f};
  f32x4 acc_o[4][2];
#pragma unroll
  for (int dt = 0; dt < 4; dt++)
#pragma unroll
    for (int m = 0; m < 2; m++){ acc_o[dt][m][0]=0.f; acc_o[dt][m][1]=0.f; acc_o[dt][m][2]=0.f; acc_o[dt][m][3]=0.f; }

  for (int c = 0; c < 4; c++){
    int key0 = t0 - 128 + c * 64;
#pragma unroll
    for (int it = 0; it < 2; ++it){
      int idx = it * 256 + tid;
      int key = idx >> 3, dd = (idx & 7) << 3;
      int gk = key0 + key;
      uint4 kq = make_uint4(0, 0, 0, 0);
      uint4 vq = make_uint4(0, 0, 0, 0);
      if (gk >= 0){
        size_t rb = (size_t)(b * 1024 + gk) * 5120;
        kq = *(const uint4*)&qkv[rb + kcol + dd];
        vq = *(const uint4*)&qkv[rb + vcol + dd];
      }
      *(uint4*)&Ks[key][dd] = kq;
      const u16* tv = (const u16*)&vq;
#pragma unroll
      for (int j = 0; j < 8; j++) VTs[dd + j][key] = tv[j];
    }
    __syncthreads();

    bool rel = (key0 + 63 >= tq0 - (win - 1)) && (key0 <= tq0 + 31);
    if (rel){
      f32x4 sacc[2][4];
#pragma unroll
      for (int m = 0; m < 2; m++)
#pragma unroll
        for (int n = 0; n < 4; n++){ sacc[m][n][0]=0.f; sacc[m][n][1]=0.f; sacc[m][n][2]=0.f; sacc[m][n][3]=0.f; }
#pragma unroll
      for (int kk = 0; kk < 2; kk++){
#pragma unroll
        for (int n = 0; n < 4; n++){
          bf16x8 kf = *(const bf16x8*)&Ks[n * 16 + lr][kk * 32 + lh * 8];
          sacc[0][n] = MFMA16(kf, qf[0][kk], sacc[0][n]);
          sacc[1][n] = MFMA16(kf, qf[1][kk], sacc[1][n]);
        }
      }
#pragma unroll
      for (int m = 0; m < 2; m++){
        int qrow = tq0 + m * 16 + lr;
        float cmax = -INFINITY;
#pragma unroll
        for (int n = 0; n < 4; n++)
#pragma unroll
          for (int r = 0; r < 4; r++){
            int key = key0 + n * 16 + lh * 4 + r;
            float s = scrub(sacc[m][n][r] * 0.125f, 1e30f);
            bool valid = (key >= 0) && (key <= qrow) && (qrow - key < win);
            s = valid ? s : -INFINITY;
            sacc[m][n][r] = s;
            cmax = fmaxf(cmax, s);
          }
        cmax = fmaxf(cmax, __shfl_xor(cmax, 16));
        cmax = fmaxf(cmax, __shfl_xor(cmax, 32));
        float mnew = fmaxf(run_max[m], cmax);
        float corr = __expf(run_max[m] - mnew);
        run_max[m] = mnew;
        float rsum = 0.f;
#pragma unroll
        for (int n = 0; n < 4; n++)
#pragma unroll
          for (int r = 0; r < 4; r++){
            float p = __expf(sacc[m][n][r] - mnew);
            sacc[m][n][r] = p;
            rsum += p;
          }
        rsum += __shfl_xor(rsum, 16);
        rsum += __shfl_xor(rsum, 32);
        run_sum[m] = run_sum[m] * corr + rsum;
#pragma unroll
        for (int dt = 0; dt < 4; dt++) acc_o[dt][m] *= corr;
#pragma unroll
        for (int n = 0; n < 4; n++)
#pragma unroll
          for (int r = 0; r < 4; r++)
            Plds[w][m * 16 + lr][n * 16 + lh * 4 + r] = f2b(sacc[m][n][r]);
      }
#pragma unroll
      for (int ks = 0; ks < 2; ks++){
        bf16x8 pb[2];
#pragma unroll
        for (int m = 0; m < 2; m++)
          pb[m] = *(const bf16x8*)&Plds[w][m * 16 + lr][ks * 32 + lh * 8];
#pragma unroll
        for (int dt = 0; dt < 4; dt++){
          bf16x8 vf = *(const bf16x8*)&VTs[dt * 16 + lr][ks * 32 + lh * 8];
          acc_o[dt][0] = MFMA16(vf, pb[0], acc_o[dt][0]);
          acc_o[dt][1] = MFMA16(vf, pb[1], acc_o[dt][1]);
        }
      }
    }
    __syncthreads();
  }

  float sk = sink[h];
  float osc[2];
#pragma unroll
  for (int m = 0; m < 2; m++){
    float Mf = fmaxf(run_max[m], sk);
    float t = __expf(run_max[m] - Mf);
    float denom = run_sum[m] * t + __expf(sk - Mf);
    osc[m] = t / denom;
  }
#pragma unroll
  for (int dt = 0; dt < 4; dt++)
#pragma unroll
    for (int m = 0; m < 2; m++)
#pragma unroll
      for (int r = 0; r < 4; r++){
        int d = dt * 16 + lh * 4 + r;
        int q = tq0 + m * 16 + lr;
        y[(size_t)(b * 1024 + q) * 4096 + h * 64 + d] = f2b(scrub(acc_o[dt][m][r] * osc[m], 1e9f));
      }
}

// ---------------- host ----------------
extern "C" void kernel_launch(void* const* d_in, const int* in_sizes, int n_in,
                              void* d_out, int out_size, void* d_ws, size_t ws_size,
                              hipStream_t stream){
  const float* x    = (const float*)d_in[0];
  const int*   pos  = (const int*)d_in[1];
  const float* Wq   = (const float*)d_in[3];
  const float* bq   = (const float*)d_in[4];
  const float* Wk   = (const float*)d_in[5];
  const float* bk   = (const float*)d_in[6];
  const float* Wv   = (const float*)d_in[7];
  const float* bv   = (const float*)d_in[8];
  const float* Wo   = (const float*)d_in[9];
  const float* bo   = (const float*)d_in[10];
  const float* sink = (const float*)d_in[11];
  const int* slide  = (const int*)d_in[12];
  const int* winp   = (const int*)d_in[13];
  float* out = (float*)d_out;

  // Workspace (61.35 MB peak, proven):
  char* ws = (char*)d_ws;
  u16*   xb   = (u16*)(ws + 0);
  u16*   ybuf = (u16*)(ws + 0);
  u16*   qkv  = (u16*)(ws + 16777216);
  u16*   wqT  = (u16*)(ws + 37748736);
  u16*   wkvT = (u16*)(ws + 37748736);
  u16*   woT  = (u16*)(ws + 37748736);
  float* bkv  = (float*)(ws + 61341696);

  // prep1: x->bf16 + WqT
  k_prep1<<<5760 + 11520, 256, 0, stream>>>(xb, x, wqT, Wq);
  // Q projection + fused RoPE: M=2048,N=4096,K=2880 -> 8x32 = 256 WGs
  k_gemm8p<0, 1><<<256, 512, 0, stream>>>(xb, wqT, bq, qkv, pos, 2048, 4096, 2880, 5120);
  // prep2: WkT+WvT+bkv
  k_prep2<<<1440 + 1440 + 4, 256, 0, stream>>>(wkvT, Wk, Wv, bkv, bk, bv);
  // KV projection + fused RoPE on k-cols: N=1024 -> 16x16 = 256 WGs
  k_gemm_bt64<0, 1><<<16 * 16, 256, 0, stream>>>(xb, wkvT, bkv, qkv + 4096, pos, 2048, 1024, 2880, 5120);
  // prep3: WoT
  k_prep3<<<11520, 256, 0, stream>>>(woT, Wo);
  // attention
  k_attn<<<1024, 256, 0, stream>>>(qkv, sink, ybuf, slide, winp);
  // output projection: M=2048,N=2880,K=4096 -> 8x23 = 184 WGs (fp32 out, ragged N)
  k_gemm8p<1, 0><<<184, 512, 0, stream>>>(ybuf, woT, bo, out, pos, 2048, 2880, 4096, 2880);
}